// Round 5
// baseline (666.038 us; speedup 1.0000x reference)
//
#include <hip/hip_runtime.h>
#include <hip/hip_fp16.h>
#include <math.h>

#define NN 100000
#define EE 1200000
#define CAP 64   // bucket capacity per dst; Poisson(12) => P(deg>64) ~ 1e-28, clamped anyway

__device__ __forceinline__ float leakyf(float x, float s) {
    return x >= 0.f ? x : s * x;
}

// ---------------- bucket-CSR build: ONE returning-atomic pass, no scan/rank ----------------
// cnt must be zeroed. col layout: col[dst*CAP + arrival], arrival from the atomic.
__global__ void fill_bucket(const int* __restrict__ ei, const int* __restrict__ rei,
                            int* __restrict__ cnt1, int* __restrict__ cnt2,
                            int* __restrict__ col1, int* __restrict__ col2) {
    int e = blockIdx.x * 256 + threadIdx.x;   // grid is exactly 2*EE threads
    if (e < EE) {
        int d = ei[EE + e];
        int p = atomicAdd(&cnt1[d], 1);
        if (p < CAP) col1[d * CAP + p] = ei[e];
    } else {
        int i = e - EE;
        int d = rei[EE + i];
        int p = atomicAdd(&cnt2[d], 1);
        if (p < CAP) col2[d * CAP + p] = rei[i];
    }
}

// ---------------- GEMM building blocks (64x64 tile, thread = 4 rows x 4 cols) ----------------

__device__ __forceinline__ void load_w(const float* __restrict__ W, float (*__restrict__ L)[64],
                                       int tid) {
    #pragma unroll
    for (int j = 0; j < 4; ++j) {
        int idx = tid + j * 256;          // float4 index 0..1023
        *(float4*)&L[idx >> 4][(idx & 15) * 4] = *(const float4*)&W[idx * 4];
    }
}

__device__ __forceinline__ void load_tile(const float* __restrict__ G, int row0,
                                          float (*__restrict__ L)[64], int tid) {
    #pragma unroll
    for (int j = 0; j < 4; ++j) {
        int idx = tid + j * 256;
        int r = idx >> 4, c4 = idx & 15;
        int row = row0 + r;
        float4 v = make_float4(0.f, 0.f, 0.f, 0.f);
        if (row < NN) v = *(const float4*)&G[(size_t)row * 64 + c4 * 4];
        *(float4*)&L[r][c4 * 4] = v;
    }
}

// acc[i] (rows r0..r0+3, cols 4q..4q+3) += Al-rows @ Wl
// unroll 2 only: full unroll blew VGPR budget (R2: 256 VGPR + 1.6GB spill traffic)
__device__ __forceinline__ void mm64(const float (*__restrict__ Al)[64],
                                     const float (*__restrict__ Wl)[64],
                                     int r0, int q, float4* acc) {
    #pragma unroll 2
    for (int k0 = 0; k0 < 64; k0 += 4) {
        float4 w0 = *(const float4*)&Wl[k0 + 0][q * 4];
        float4 w1 = *(const float4*)&Wl[k0 + 1][q * 4];
        float4 w2 = *(const float4*)&Wl[k0 + 2][q * 4];
        float4 w3 = *(const float4*)&Wl[k0 + 3][q * 4];
        #pragma unroll
        for (int i = 0; i < 4; ++i) {
            float4 a = *(const float4*)&Al[r0 + i][k0];
            acc[i].x = fmaf(a.x, w0.x, acc[i].x); acc[i].x = fmaf(a.y, w1.x, acc[i].x);
            acc[i].x = fmaf(a.z, w2.x, acc[i].x); acc[i].x = fmaf(a.w, w3.x, acc[i].x);
            acc[i].y = fmaf(a.x, w0.y, acc[i].y); acc[i].y = fmaf(a.y, w1.y, acc[i].y);
            acc[i].y = fmaf(a.z, w2.y, acc[i].y); acc[i].y = fmaf(a.w, w3.y, acc[i].y);
            acc[i].z = fmaf(a.x, w0.z, acc[i].z); acc[i].z = fmaf(a.y, w1.z, acc[i].z);
            acc[i].z = fmaf(a.z, w2.z, acc[i].z); acc[i].z = fmaf(a.w, w3.z, acc[i].z);
            acc[i].w = fmaf(a.x, w0.w, acc[i].w); acc[i].w = fmaf(a.y, w1.w, acc[i].w);
            acc[i].w = fmaf(a.z, w2.w, acc[i].w); acc[i].w = fmaf(a.w, w3.w, acc[i].w);
        }
    }
}

// epilogue: store hW as fp16 (halves gather traffic in aggregate), a_s/a_d row dots
__device__ __forceinline__ void att_epilogue(const float4* acc, int row0, int r0, int q, int tid,
                                             const float* __restrict__ att_s,
                                             const float* __restrict__ att_d,
                                             __half* __restrict__ hW,
                                             float* __restrict__ a_s,
                                             float* __restrict__ a_d) {
    float4 as4 = *(const float4*)&att_s[q * 4];
    float4 ad4 = *(const float4*)&att_d[q * 4];
    #pragma unroll
    for (int i = 0; i < 4; ++i) {
        int row = row0 + r0 + i;
        if (row < NN) {
            union { float2 f2; __half2 h2[2]; } u;
            u.h2[0] = __floats2half2_rn(acc[i].x, acc[i].y);
            u.h2[1] = __floats2half2_rn(acc[i].z, acc[i].w);
            *(float2*)&hW[(size_t)row * 64 + q * 4] = u.f2;
        }
        float ps = acc[i].x * as4.x + acc[i].y * as4.y + acc[i].z * as4.z + acc[i].w * as4.w;
        float pd = acc[i].x * ad4.x + acc[i].y * ad4.y + acc[i].z * ad4.z + acc[i].w * ad4.w;
        #pragma unroll
        for (int off = 1; off < 16; off <<= 1) {
            ps += __shfl_xor(ps, off);
            pd += __shfl_xor(pd, off);
        }
        if ((tid & 15) == 0 && row < NN) { a_s[row] = ps; a_d[row] = pd; }
    }
}

// fused: h = leaky(x@W1+b1, .01); hW = h@Wc; a_s/a_d row dots
__global__ __launch_bounds__(256, 4) void lin1_pre_gat(
        const float* __restrict__ x, const float* __restrict__ W1, const float* __restrict__ b1,
        const float* __restrict__ Wc, const float* __restrict__ att_s, const float* __restrict__ att_d,
        __half* __restrict__ hW, float* __restrict__ a_s, float* __restrict__ a_d) {
    __shared__ float Al[64][64];
    __shared__ float Wl[64][64];
    const int tid = threadIdx.x, row0 = blockIdx.x * 64;
    load_w(W1, Wl, tid);
    load_tile(x, row0, Al, tid);
    __syncthreads();
    const int r0 = (tid >> 4) * 4, q = tid & 15;
    float4 acc[4] = {{0,0,0,0},{0,0,0,0},{0,0,0,0},{0,0,0,0}};
    mm64(Al, Wl, r0, q, acc);
    __syncthreads();   // reads of Al/Wl done; reuse Al as H tile, Wl for Wc
    load_w(Wc, Wl, tid);
    float4 bb = *(const float4*)&b1[q * 4];
    #pragma unroll
    for (int i = 0; i < 4; ++i) {
        float4 h;
        h.x = leakyf(acc[i].x + bb.x, 0.01f);
        h.y = leakyf(acc[i].y + bb.y, 0.01f);
        h.z = leakyf(acc[i].z + bb.z, 0.01f);
        h.w = leakyf(acc[i].w + bb.w, 0.01f);
        *(float4*)&Al[r0 + i][q * 4] = h;
        acc[i] = make_float4(0.f, 0.f, 0.f, 0.f);
    }
    __syncthreads();
    mm64(Al, Wl, r0, q, acc);
    att_epilogue(acc, row0, r0, q, tid, att_s, att_d, hW, a_s, a_d);
}

// hW = H@Wc; a_s/a_d row dots
__global__ __launch_bounds__(256, 4) void pre_gat(
        const float* __restrict__ H, const float* __restrict__ Wc,
        const float* __restrict__ att_s, const float* __restrict__ att_d,
        __half* __restrict__ hW, float* __restrict__ a_s, float* __restrict__ a_d) {
    __shared__ float Al[64][64];
    __shared__ float Wcl[64][64];
    const int tid = threadIdx.x, row0 = blockIdx.x * 64;
    load_w(Wc, Wcl, tid);
    load_tile(H, row0, Al, tid);
    __syncthreads();
    const int r0 = (tid >> 4) * 4, q = tid & 15;
    float4 acc[4] = {{0,0,0,0},{0,0,0,0},{0,0,0,0},{0,0,0,0}};
    mm64(Al, Wcl, r0, q, acc);
    att_epilogue(acc, row0, r0, q, tid, att_s, att_d, hW, a_s, a_d);
}

// out = [A0 ++ A1] @ W2 + b2  (time-shared W buffer)
__global__ __launch_bounds__(256, 4) void final_gemm(
        const float* __restrict__ A0, const float* __restrict__ A1,
        const float* __restrict__ W2, const float* __restrict__ b2, float* __restrict__ out) {
    __shared__ float Al[64][64];
    __shared__ float Wl[64][64];
    const int tid = threadIdx.x, row0 = blockIdx.x * 64;
    load_w(W2, Wl, tid);
    load_tile(A0, row0, Al, tid);
    __syncthreads();
    const int r0 = (tid >> 4) * 4, q = tid & 15;
    float4 bb = *(const float4*)&b2[q * 4];
    float4 acc[4] = {bb, bb, bb, bb};
    mm64(Al, Wl, r0, q, acc);
    __syncthreads();
    load_w(W2 + 4096, Wl, tid);
    load_tile(A1, row0, Al, tid);
    __syncthreads();
    mm64(Al, Wl, r0, q, acc);
    #pragma unroll
    for (int i = 0; i < 4; ++i) {
        int row = row0 + r0 + i;
        if (row < NN) *(float4*)&out[(size_t)row * 64 + q * 4] = acc[i];
    }
}

// ---------------- fused segment-softmax aggregate (bucket gather, no atomics) ----------------
// one wave per dst node; lane == channel; per-lane exp hoisted; col read is coalesced
__global__ __launch_bounds__(256) void aggregate(
        const int* __restrict__ cnt, const int* __restrict__ col,
        const float* __restrict__ a_s, const float* __restrict__ a_d,
        const __half* __restrict__ hW, const float* __restrict__ bias,
        float* __restrict__ out) {
    const int wave = threadIdx.x >> 6, lane = threadIdx.x & 63;
    const int d = blockIdx.x * 4 + wave;
    if (d >= NN) return;
    int deg = cnt[d];
    if (deg > CAP) deg = CAP;               // overflow guard (never hit for this dataset)
    const float ad = a_d[d];
    const float vself = leakyf(a_s[d] + ad, 0.2f);

    // each lane owns one bucket slot (coalesced 256B line per wave)
    int s_l = 0;
    float v_l = -1e30f;
    if (lane < deg) {
        s_l = col[d * CAP + lane];
        v_l = leakyf(a_s[s_l] + ad, 0.2f);
    }
    float mx = fmaxf(vself, v_l);
    #pragma unroll
    for (int off = 32; off; off >>= 1) mx = fmaxf(mx, __shfl_xor(mx, off));

    // per-lane exp once; den via butterfly reduce
    float ex_l = (lane < deg) ? __expf(v_l - mx) : 0.f;
    float den = ex_l;
    #pragma unroll
    for (int off = 32; off; off >>= 1) den += __shfl_xor(den, off);
    float exself = __expf(vself - mx);
    den += exself;
    float acc = exself * __half2float(hW[(size_t)d * 64 + lane]);

    int idx = 0;
    for (; idx + 4 <= deg; idx += 4) {      // 4-wide: 4 independent row loads in flight
        int   s0 = __shfl(s_l, idx),     s1 = __shfl(s_l, idx + 1);
        int   s2 = __shfl(s_l, idx + 2), s3 = __shfl(s_l, idx + 3);
        float e0 = __shfl(ex_l, idx),     e1 = __shfl(ex_l, idx + 1);
        float e2 = __shfl(ex_l, idx + 2), e3 = __shfl(ex_l, idx + 3);
        float r0v = __half2float(hW[(size_t)s0 * 64 + lane]);
        float r1v = __half2float(hW[(size_t)s1 * 64 + lane]);
        float r2v = __half2float(hW[(size_t)s2 * 64 + lane]);
        float r3v = __half2float(hW[(size_t)s3 * 64 + lane]);
        acc = fmaf(e0, r0v, acc); acc = fmaf(e1, r1v, acc);
        acc = fmaf(e2, r2v, acc); acc = fmaf(e3, r3v, acc);
    }
    for (; idx < deg; ++idx) {
        int   s = __shfl(s_l, idx);
        float e = __shfl(ex_l, idx);
        acc = fmaf(e, __half2float(hW[(size_t)s * 64 + lane]), acc);
    }
    out[(size_t)d * 64 + lane] = acc / (den + 1e-16f) + bias[lane];
}

// ---------------- launch ----------------

extern "C" void kernel_launch(void* const* d_in, const int* in_sizes, int n_in,
                              void* d_out, int out_size, void* d_ws, size_t ws_size,
                              hipStream_t stream) {
    const float* x      = (const float*)d_in[0];
    const int*   ei     = (const int*)  d_in[1];   // src = ei, dst = ei + EE
    const float* rg_x   = (const float*)d_in[3];
    const int*   rei    = (const int*)  d_in[4];
    const float* W1     = (const float*)d_in[6];
    const float* b1     = (const float*)d_in[7];
    const float* atom_W  = (const float*)d_in[8];
    const float* atom_as = (const float*)d_in[9];
    const float* atom_ad = (const float*)d_in[10];
    const float* atom_b  = (const float*)d_in[11];
    const float* rg_W    = (const float*)d_in[12];
    const float* rg_as   = (const float*)d_in[13];
    const float* rg_ad   = (const float*)d_in[14];
    const float* rg_b    = (const float*)d_in[15];
    const float* mol_W   = (const float*)d_in[16];
    const float* mol_as  = (const float*)d_in[17];
    const float* mol_ad  = (const float*)d_in[18];
    const float* mol_b   = (const float*)d_in[19];
    const float* W2     = (const float*)d_in[20];
    const float* b2     = (const float*)d_in[21];

    // workspace layout
    float* fp   = (float*)d_ws;
    float* bufX = fp;                       fp += (size_t)NN * 64;   // atom out -> mol out
    float* rgO  = fp;                       fp += (size_t)NN * 64;
    float* a_s  = fp;                       fp += NN;
    float* a_d  = fp;                       fp += NN;
    __half* hW  = (__half*)fp;              fp += (size_t)NN * 32;   // NN*64 halves
    int* ip = (int*)fp;
    int* cnt1 = ip;            ip += NN;    // cnt1/cnt2 contiguous: single memset
    int* cnt2 = ip;            ip += NN;
    int* col1 = ip;            ip += (size_t)NN * CAP;
    int* col2 = ip;            ip += (size_t)NN * CAP;

    const dim3 blk(256);
    const int gE2  = (2 * EE + 255) / 256;      // exactly 2*EE threads (2*EE % 256 == 0)
    const int gT   = (NN + 63) / 64;            // 64-row GEMM tiles
    const int gAgg = (NN + 3) / 4;

    hipMemsetAsync(cnt1, 0, (size_t)2 * NN * 4, stream);

    // bucket-CSR for both graphs in one atomic pass (atom graph reused by mol conv)
    fill_bucket<<<gE2, blk, 0, stream>>>(ei, rei, cnt1, cnt2, col1, col2);

    // atom conv (fused lin1)
    lin1_pre_gat<<<gT, blk, 0, stream>>>(x, W1, b1, atom_W, atom_as, atom_ad, hW, a_s, a_d);
    aggregate<<<gAgg, blk, 0, stream>>>(cnt1, col1, a_s, a_d, hW, atom_b, bufX);
    // rg conv (fused lin1)
    lin1_pre_gat<<<gT, blk, 0, stream>>>(rg_x, W1, b1, rg_W, rg_as, rg_ad, hW, a_s, a_d);
    aggregate<<<gAgg, blk, 0, stream>>>(cnt2, col2, a_s, a_d, hW, rg_b, rgO);
    // mol conv on atom output
    pre_gat<<<gT, blk, 0, stream>>>(bufX, mol_W, mol_as, mol_ad, hW, a_s, a_d);
    aggregate<<<gAgg, blk, 0, stream>>>(cnt1, col1, a_s, a_d, hW, mol_b, bufX);
    // final concat GEMM
    final_gemm<<<gT, blk, 0, stream>>>(bufX, rgO, W2, b2, (float*)d_out);
}